// Round 1
// baseline (175.297 us; speedup 1.0000x reference)
//
#include <hip/hip_runtime.h>
#include <math.h>

#define IMG_H 4096
#define IMG_W 4096

__global__ __launch_bounds__(256) void nms_kernel(const float* __restrict__ img,
                                                  const float* __restrict__ theta,
                                                  float* __restrict__ out) {
    const int tid = blockIdx.x * blockDim.x + threadIdx.x;   // one thread = 4 pixels
    const int x  = tid >> 10;            // row (W/4 = 1024 threads per row)
    const int y4 = (tid & 1023) << 2;    // starting column of this thread's 4-px chunk

    const long long base = (long long)x * IMG_W + y4;

    const int xu = (x > 0)        ? x - 1 : 0;        // clamped; border rows output 0 anyway
    const int xd = (x < IMG_H - 1) ? x + 1 : IMG_H - 1;

    const float* rowc = img + (long long)x  * IMG_W;
    const float* rowu = img + (long long)xu * IMG_W;
    const float* rowd = img + (long long)xd * IMG_W;

    // vector loads of the three rows + theta
    const float4 c = *(const float4*)(rowc + y4);
    const float4 u = *(const float4*)(rowu + y4);
    const float4 d = *(const float4*)(rowd + y4);
    const float4 th = *(const float4*)(theta + base);

    // one-column-shifted edge scalars (clamped; unused when the consuming pixel is a border)
    const int yl = (y4 > 0)           ? y4 - 1 : 0;
    const int yr = (y4 + 4 < IMG_W)   ? y4 + 4 : IMG_W - 1;
    const float cl = rowc[yl], cr = rowc[yr];
    const float ul = rowu[yl], ur = rowu[yr];
    const float dl = rowd[yl], dr = rowd[yr];

    const float cv[6] = {cl, c.x, c.y, c.z, c.w, cr};
    const float uv[6] = {ul, u.x, u.y, u.z, u.w, ur};
    const float dv[6] = {dl, d.x, d.y, d.z, d.w, dr};
    const float tv[4] = {th.x, th.y, th.z, th.w};

    float ov[4];
    const bool row_interior = (x > 0) && (x < IMG_H - 1);

    #pragma unroll
    for (int i = 0; i < 4; ++i) {
        const float v = cv[i + 1];

        // ---- quantize angle exactly like the reference (float32 path) ----
        // deg = theta * float32(180/pi); if (deg<0) deg += 180;
        // q = round_half_even(deg / 45) * 45; (q==180 -> 0, then chain-compare)
        float deg = tv[i] * 57.29577951308232f;
        if (deg < 0.0f) deg += 180.0f;
        float q = rintf(deg / 45.0f) * 45.0f;
        if (q == 180.0f) q = 0.0f;

        float a, b;
        if (q == 0.0f) {          // compare (x, y+1), (x, y-1)
            a = cv[i + 2]; b = cv[i];
        } else if (q == 45.0f) {  // compare (x+1, y+1), (x-1, y-1)
            a = dv[i + 2]; b = uv[i];
        } else if (q == 90.0f) {  // compare (x+1, y), (x-1, y)
            a = dv[i + 1]; b = uv[i + 1];
        } else {                  // m135 (incl. negative / >135 q): (x+1,y-1), (x-1,y+1)
            a = dv[i]; b = uv[i + 2];
        }

        const int y = y4 + i;
        const bool interior = row_interior && (y > 0) && (y < IMG_W - 1);
        const bool mask = (v >= a) && (v >= b);
        ov[i] = (mask && interior) ? v : 0.0f;
    }

    float4 o;
    o.x = ov[0]; o.y = ov[1]; o.z = ov[2]; o.w = ov[3];
    *(float4*)(out + base) = o;
}

extern "C" void kernel_launch(void* const* d_in, const int* in_sizes, int n_in,
                              void* d_out, int out_size, void* d_ws, size_t ws_size,
                              hipStream_t stream) {
    const float* img   = (const float*)d_in[0];
    const float* theta = (const float*)d_in[1];
    float* out = (float*)d_out;

    const int total_threads = IMG_H * (IMG_W / 4);   // 4 px per thread
    const int block = 256;
    const int grid = total_threads / block;          // 16384
    nms_kernel<<<grid, block, 0, stream>>>(img, theta, out);
}